// Round 6
// baseline (64.619 us; speedup 1.0000x reference)
//
#include <hip/hip_runtime.h>
#include <hip/hip_cooperative_groups.h>

namespace cg = cooperative_groups;

// YOLO loss: B=32, A=5, C=80, gh=gw=52, HW=2704.
// d_in[0] net_out (B,A,85,HW) f32 | d_in[1] targets (B,A,6,HW) f32 (pre-masked)
// d_in[2] anchor_mask (B,A,HW) {0,1} | d_in[3] obj_mask (B,A,HW) {0,1}
// d_in[4] anchors (5,2) f32.  Output: scalar f32.
//
// Single cooperative dispatch: per-block partials -> grid.sync() -> block 0
// reduces -> plain store to out. No memset, no atomics to out, no manual
// cross-block protocol (R4's hand-rolled ticket was both slow and unsafe).

constexpr int B_  = 32;
constexpr int A_  = 5;
constexpr int C_  = 80;
constexpr int GW_ = 52;
constexpr int GH_ = 52;
constexpr int HW_ = GW_ * GH_;        // 2704 (divisible by 4)
constexpr int NCH = 5 + C_;           // 85
constexpr int TOTAL = B_ * A_ * HW_;  // 432640
constexpr int BLOCK = 256;
constexpr int CPT   = 4;              // cells per thread (float4 dense loads)
constexpr int GRID  = (TOTAL + BLOCK * CPT - 1) / (BLOCK * CPT);  // 423

constexpr float NET_W = 416.0f;
constexpr float NET_H = 416.0f;
constexpr float OBJ_THRESH  = 0.5f;
constexpr float COORD_SCALE = 5.0f;
constexpr float NOOBJ_SCALE = 1.0f;
constexpr float OBJ_SCALE   = 5.0f;
constexpr float CLASS_SCALE = 1.0f;

__device__ __forceinline__ float sigmoidf_(float x) {
    return 1.0f / (1.0f + __expf(-x));
}

// Per-cell terms: noobj1 + (coords+obj | IOU-gated noobj). Sets tc on CE cells.
__device__ __forceinline__ float cell_terms(
    const float* __restrict__ net, const float* __restrict__ tgt,
    unsigned nbase, unsigned tbase, int hw, float aw, float ah,
    float om, float diff2, bool want_ce, int& tc)
{
    float loss = diff2 * (1.0f - om) * NOOBJ_SCALE;   // noobj1 (dense)

    const bool need_box = want_ce || (om != 0.0f);
    if (!need_box) return loss;

    const float p0 = net[nbase + 0u * HW_];
    const float p1 = net[nbase + 1u * HW_];
    const float p2 = net[nbase + 2u * HW_];
    const float p3 = net[nbase + 3u * HW_];
    const float t0 = tgt[tbase + 0u * HW_];
    const float t1 = tgt[tbase + 1u * HW_];
    const float t2 = tgt[tbase + 2u * HW_];
    const float t3 = tgt[tbase + 3u * HW_];

    const float sx = sigmoidf_(p0);
    const float sy = sigmoidf_(p1);

    if (want_ce) {
        const float dx = sx - t0;
        const float dy = sy - t1;
        const float pws = __expf(p2) * aw * (1.0f / NET_W);
        const float phs = __expf(p3) * ah * (1.0f / NET_H);
        const float tws = __expf(t2) * aw * (1.0f / NET_W);
        const float ths = __expf(t3) * ah * (1.0f / NET_H);
        const float dw = pws - tws;
        const float dh = phs - ths;
        loss += (dx * dx + dy * dy + dw * dw + dh * dh) * COORD_SCALE;
        loss += diff2 * OBJ_SCALE;
        tc = (int)tgt[tbase + 5u * HW_];
    } else {
        // no_resp: om==1, cm==0 -> IOU-gated noobj term
        const float col = (float)(hw % GW_);
        const float row = (float)(hw / GW_);

        const float pcx = (sx + col) * (NET_W / (float)GW_);
        const float pcy = (sy + row) * (NET_H / (float)GH_);
        const float pw  = __expf(p2) * aw;
        const float ph  = __expf(p3) * ah;
        const float px1 = pcx - 0.5f * pw;
        const float py1 = pcy - 0.5f * ph;
        const float px2 = px1 + pw;
        const float py2 = py1 + ph;

        const float gcx = (t0 + col) * (NET_W / (float)GW_);
        const float gcy = (t1 + row) * (NET_H / (float)GH_);
        const float gwd = __expf(t2) * aw;
        const float ghd = __expf(t3) * ah;
        const float gx1 = gcx - 0.5f * gwd;
        const float gy1 = gcy - 0.5f * ghd;
        const float gx2 = gx1 + gwd;
        const float gy2 = gy1 + ghd;

        const float iw = fmaxf(fminf(px2, gx2) - fmaxf(px1, gx1), 0.0f);
        const float ih = fmaxf(fminf(py2, gy2) - fmaxf(py1, gy1), 0.0f);
        const float inter  = iw * ih;
        const float area_p = (px2 - px1) * (py2 - py1);
        const float area_g = (gx2 - gx1) * (gy2 - gy1);
        const float iou = inter / (area_p + area_g - inter + 1e-9f);
        if (iou < OBJ_THRESH) loss += diff2 * NOOBJ_SCALE;
    }
    return loss;
}

__global__ __launch_bounds__(256) void yolo_coop_kernel(
    const float* __restrict__ net,     // (B*A*85*HW)
    const float* __restrict__ tgt,     // (B*A*6*HW)
    const float* __restrict__ amask,   // (B*A*HW)
    const float* __restrict__ omask,   // (B*A*HW)
    const float* __restrict__ anchors, // (5*2)
    float* __restrict__ partial,       // (GRID) in d_ws
    float* __restrict__ out)
{
    const int t    = blockIdx.x * blockDim.x + threadIdx.x;
    const int lane = threadIdx.x & 63;

    const int  cell0 = CPT * t;            // multiple of 4; group never
    const bool act   = (cell0 < TOTAL);    // straddles a ba boundary (HW_%4==0)

    float loss = 0.0f;
    bool ces0 = false, ces1 = false, ces2 = false, ces3 = false;
    int  tc0 = 0, tc1 = 0, tc2 = 0, tc3 = 0;
    unsigned nbase0 = 0;

    if (act) {
        const int hw0 = cell0 % HW_;
        const int ba  = cell0 / HW_;
        const int a   = ba % A_;

        nbase0 = (unsigned)ba * (unsigned)(NCH * HW_) + (unsigned)hw0;
        const unsigned tbase0 = (unsigned)ba * (unsigned)(6 * HW_) + (unsigned)hw0;

        // dense 16B/lane vector loads (aligned: cell0 % 4 == 0)
        const float4 am4 = *reinterpret_cast<const float4*>(amask + cell0);
        const float4 om4 = *reinterpret_cast<const float4*>(omask + cell0);
        const float4 cf4 = *reinterpret_cast<const float4*>(net + nbase0 + 4u * HW_);

        const float aw = anchors[2 * a];
        const float ah = anchors[2 * a + 1];

        {   // slot 0
            ces0 = (am4.x != 0.0f);
            const float conf  = sigmoidf_(cf4.x);
            const float tcf   = ces0 ? tgt[tbase0 + 0u + 4u * HW_] : 0.0f;
            const float d     = conf - tcf;
            loss += cell_terms(net, tgt, nbase0 + 0u, tbase0 + 0u, hw0 + 0,
                               aw, ah, om4.x, d * d, ces0, tc0);
        }
        {   // slot 1
            ces1 = (am4.y != 0.0f);
            const float conf  = sigmoidf_(cf4.y);
            const float tcf   = ces1 ? tgt[tbase0 + 1u + 4u * HW_] : 0.0f;
            const float d     = conf - tcf;
            loss += cell_terms(net, tgt, nbase0 + 1u, tbase0 + 1u, hw0 + 1,
                               aw, ah, om4.y, d * d, ces1, tc1);
        }
        {   // slot 2
            ces2 = (am4.z != 0.0f);
            const float conf  = sigmoidf_(cf4.z);
            const float tcf   = ces2 ? tgt[tbase0 + 2u + 4u * HW_] : 0.0f;
            const float d     = conf - tcf;
            loss += cell_terms(net, tgt, nbase0 + 2u, tbase0 + 2u, hw0 + 2,
                               aw, ah, om4.z, d * d, ces2, tc2);
        }
        {   // slot 3
            ces3 = (am4.w != 0.0f);
            const float conf  = sigmoidf_(cf4.w);
            const float tcf   = ces3 ? tgt[tbase0 + 3u + 4u * HW_] : 0.0f;
            const float d     = conf - tcf;
            loss += cell_terms(net, tgt, nbase0 + 3u, tbase0 + 3u, hw0 + 3,
                               aw, ah, om4.w, d * d, ces3, tc3);
        }
    }

    // ---- wave-cooperative class CE: 4 events/iteration, 16 lanes/event ----
    {
        unsigned long long m0 = __ballot(ces0);
        unsigned long long m1 = __ballot(ces1);
        unsigned long long m2 = __ballot(ces2);
        unsigned long long m3 = __ballot(ces3);

        const int nb_i = (int)nbase0;
        const int tcpack = (tc0 & 0xff) | ((tc1 & 0xff) << 8)
                         | ((tc2 & 0xff) << 16) | ((tc3 & 0xff) << 24);
        const int g = lane >> 4;   // 16-lane group 0..3
        const int j = lane & 15;

        while (m0 | m1 | m2 | m3) {
            int e0 = -1, e1 = -1, e2 = -1, e3 = -1;
#define POP_EV(dst)                                                          \
            if (m0)      { dst = (__ffsll((long long)m0) - 1);            m0 &= m0 - 1; } \
            else if (m1) { dst = (__ffsll((long long)m1) - 1) | (1 << 6); m1 &= m1 - 1; } \
            else if (m2) { dst = (__ffsll((long long)m2) - 1) | (2 << 6); m2 &= m2 - 1; } \
            else if (m3) { dst = (__ffsll((long long)m3) - 1) | (3 << 6); m3 &= m3 - 1; }
            POP_EV(e0); POP_EV(e1); POP_EV(e2); POP_EV(e3);
#undef POP_EV

            const int evg  = (g == 0) ? e0 : (g == 1) ? e1 : (g == 2) ? e2 : e3;
            const int ev   = (evg >= 0) ? evg : e0;   // idle groups redo e0
            const int src  = ev & 63;
            const int slot = ev >> 6;

            const unsigned nb = (unsigned)__shfl(nb_i, src, 64) + (unsigned)slot;
            const int tp  = __shfl(tcpack, src, 64);
            const int tce = (tp >> (8 * slot)) & 0xff;   // target class 0..79

            // group loads its event's 80 logits: class c = j + 16k, k=0..4
            const float x0 = net[nb + (unsigned)(5 + j +  0) * HW_];
            const float x1 = net[nb + (unsigned)(5 + j + 16) * HW_];
            const float x2 = net[nb + (unsigned)(5 + j + 32) * HW_];
            const float x3 = net[nb + (unsigned)(5 + j + 48) * HW_];
            const float x4 = net[nb + (unsigned)(5 + j + 64) * HW_];

            float mx = fmaxf(fmaxf(fmaxf(x0, x1), fmaxf(x2, x3)), x4);
            #pragma unroll
            for (int off = 8; off > 0; off >>= 1)
                mx = fmaxf(mx, __shfl_xor(mx, off, 64));   // stays in 16-group

            float sm = __expf(x0 - mx) + __expf(x1 - mx) + __expf(x2 - mx)
                     + __expf(x3 - mx) + __expf(x4 - mx);
            #pragma unroll
            for (int off = 8; off > 0; off >>= 1)
                sm += __shfl_xor(sm, off, 64);

            const int j0 = tce & 15;
            const int k0 = tce >> 4;   // 0..4
            const float xk = (k0 == 0) ? x0 : (k0 == 1) ? x1 : (k0 == 2) ? x2
                           : (k0 == 3) ? x3 : x4;
            float cand = (j == j0) ? xk : -1e30f;
            #pragma unroll
            for (int off = 8; off > 0; off >>= 1)
                cand = fmaxf(cand, __shfl_xor(cand, off, 64));

            const float ce = -(cand - mx - __logf(sm));   // group-uniform

            const float c0 = __shfl(ce,  0, 64);
            const float c1 = __shfl(ce, 16, 64);
            const float c2 = __shfl(ce, 32, 64);
            const float c3 = __shfl(ce, 48, 64);
            if (e0 >= 0 && lane == (e0 & 63)) loss += c0 * CLASS_SCALE;
            if (e1 >= 0 && lane == (e1 & 63)) loss += c1 * CLASS_SCALE;
            if (e2 >= 0 && lane == (e2 & 63)) loss += c2 * CLASS_SCALE;
            if (e3 >= 0 && lane == (e3 & 63)) loss += c3 * CLASS_SCALE;
        }
    }

    // ---- block reduction -> per-block partial ----
    #pragma unroll
    for (int off = 32; off > 0; off >>= 1)
        loss += __shfl_down(loss, off, 64);

    __shared__ float wsum[4];
    const int wid = threadIdx.x >> 6;
    if (lane == 0) wsum[wid] = loss;
    __syncthreads();
    if (threadIdx.x == 0)
        partial[blockIdx.x] = wsum[0] + wsum[1] + wsum[2] + wsum[3];

    // ---- grid-wide barrier (vendor-implemented, device-scope semantics) ----
    cg::this_grid().sync();

    // ---- block 0: final reduce of GRID partials ----
    if (blockIdx.x == 0) {
        float s = 0.0f;
        for (int p = threadIdx.x; p < GRID; p += BLOCK)
            s += partial[p];
        #pragma unroll
        for (int off = 32; off > 0; off >>= 1)
            s += __shfl_down(s, off, 64);
        __shared__ float w2[4];
        if (lane == 0) w2[wid] = s;
        __syncthreads();
        if (threadIdx.x == 0)
            out[0] = w2[0] + w2[1] + w2[2] + w2[3];
    }
}

extern "C" void kernel_launch(void* const* d_in, const int* in_sizes, int n_in,
                              void* d_out, int out_size, void* d_ws, size_t ws_size,
                              hipStream_t stream) {
    const float* net     = (const float*)d_in[0];
    const float* tgt     = (const float*)d_in[1];
    const float* amask   = (const float*)d_in[2];
    const float* omask   = (const float*)d_in[3];
    const float* anchors = (const float*)d_in[4];
    float* out     = (float*)d_out;
    float* partial = (float*)d_ws;   // GRID floats, fully overwritten each launch

    void* args[] = { (void*)&net, (void*)&tgt, (void*)&amask, (void*)&omask,
                     (void*)&anchors, (void*)&partial, (void*)&out };
    hipLaunchCooperativeKernel((const void*)yolo_coop_kernel,
                               dim3(GRID), dim3(BLOCK), args, 0, stream);
}

// Round 7
// 11.815 us; speedup vs baseline: 5.4693x; 5.4693x over previous
//
#include <hip/hip_runtime.h>

// YOLO loss: B=32, A=5, C=80, gh=gw=52, HW=2704.
// d_in[0] net_out (B,A,85,HW) f32 | d_in[1] targets (B,A,6,HW) f32 (pre-masked)
// d_in[2] anchor_mask (B,A,HW) {0,1} | d_in[3] obj_mask (B,A,HW) {0,1}
// d_in[4] anchors (5,2) f32.  Output: scalar f32.
//
// BEST-KNOWN STRUCTURE (R2, 12.06us, absmax 0.0): two plain dispatches.
// Kernel 1 writes per-block partials to d_ws with plain stores; kernel 2
// (1 block) reduces them and plain-stores out[0]. Kernel-boundary implicit
// release/acquire handles cross-XCD visibility. Measured alternatives:
// memset+atomicAdd-to-out = +11..24us; manual ticket/fence = +27us AND
// numerically unsafe (cross-XCD); hipLaunchCooperativeKernel = +52us.
// Wave count (CPT 1 vs 4) and CE batching (2 vs 4 wide): null (<5%).

constexpr int B_  = 32;
constexpr int A_  = 5;
constexpr int C_  = 80;
constexpr int GW_ = 52;
constexpr int GH_ = 52;
constexpr int HW_ = GW_ * GH_;
constexpr int NCH = 5 + C_;           // 85
constexpr int TOTAL = B_ * A_ * HW_;  // 432640 = 1690 * 256 exactly
constexpr int BLOCK = 256;
constexpr int GRID  = TOTAL / BLOCK;  // 1690

constexpr float NET_W = 416.0f;
constexpr float NET_H = 416.0f;
constexpr float OBJ_THRESH  = 0.5f;
constexpr float COORD_SCALE = 5.0f;
constexpr float NOOBJ_SCALE = 1.0f;
constexpr float OBJ_SCALE   = 5.0f;
constexpr float CLASS_SCALE = 1.0f;

__device__ __forceinline__ float sigmoidf_(float x) {
    return 1.0f / (1.0f + __expf(-x));
}

__global__ __launch_bounds__(256) void yolo_partial_kernel(
    const float* __restrict__ net,     // (B*A*85*HW)
    const float* __restrict__ tgt,     // (B*A*6*HW)
    const float* __restrict__ amask,   // (B*A*HW)
    const float* __restrict__ omask,   // (B*A*HW)
    const float* __restrict__ anchors, // (5*2)
    float* __restrict__ partial)       // (GRID)
{
    const int i    = blockIdx.x * blockDim.x + threadIdx.x;  // always < TOTAL
    const int lane = threadIdx.x & 63;

    const int hw = i % HW_;
    const int ba = i / HW_;      // b*A + a
    const int a  = ba % A_;

    // all offsets fit comfortably in 32 bits (net has 36.8M elements)
    const unsigned nbase = (unsigned)ba * (unsigned)(NCH * HW_) + (unsigned)hw;
    const unsigned tbase = (unsigned)ba * (unsigned)(6 * HW_)   + (unsigned)hw;

    const float cm = amask[i];   // {0,1}
    const float om = omask[i];   // {0,1}

    const bool want_ce  = (cm != 0.0f);
    const bool need_box = want_ce || (om != 0.0f);

    // ---- dense phase: conf term (every cell) ----
    const float conf = sigmoidf_(net[nbase + 4u * HW_]);
    // targets are pre-multiplied by anchor_mask -> t_conf == 0 where cm == 0
    float t_conf = 0.0f;
    if (want_ce) t_conf = tgt[tbase + 4u * HW_];
    const float d     = conf - t_conf;
    const float diff2 = d * d;

    float loss = diff2 * (1.0f - om) * NOOBJ_SCALE;   // noobj1

    int tc = 0;  // target class, valid only on want_ce lanes
    if (need_box) {
        const float aw = anchors[2 * a];
        const float ah = anchors[2 * a + 1];

        const float p0 = net[nbase + 0u * HW_];
        const float p1 = net[nbase + 1u * HW_];
        const float p2 = net[nbase + 2u * HW_];
        const float p3 = net[nbase + 3u * HW_];
        const float t0 = tgt[tbase + 0u * HW_];
        const float t1 = tgt[tbase + 1u * HW_];
        const float t2 = tgt[tbase + 2u * HW_];
        const float t3 = tgt[tbase + 3u * HW_];

        const float sx = sigmoidf_(p0);
        const float sy = sigmoidf_(p1);

        if (want_ce) {
            const float dx = sx - t0;
            const float dy = sy - t1;
            const float pws = __expf(p2) * aw * (1.0f / NET_W);
            const float phs = __expf(p3) * ah * (1.0f / NET_H);
            const float tws = __expf(t2) * aw * (1.0f / NET_W);
            const float ths = __expf(t3) * ah * (1.0f / NET_H);
            const float dw = pws - tws;
            const float dh = phs - ths;
            loss += (dx * dx + dy * dy + dw * dw + dh * dh) * COORD_SCALE;
            loss += diff2 * OBJ_SCALE;
            tc = (int)tgt[tbase + 5u * HW_];
        } else {
            // no_resp lane: om==1, cm==0 -> IOU gate on the noobj term
            const float col = (float)(hw % GW_);
            const float row = (float)(hw / GW_);

            const float pcx = (sx + col) * (NET_W / (float)GW_);
            const float pcy = (sy + row) * (NET_H / (float)GH_);
            const float pw  = __expf(p2) * aw;
            const float ph  = __expf(p3) * ah;
            const float px1 = pcx - 0.5f * pw;
            const float py1 = pcy - 0.5f * ph;
            const float px2 = px1 + pw;
            const float py2 = py1 + ph;

            const float gcx = (t0 + col) * (NET_W / (float)GW_);
            const float gcy = (t1 + row) * (NET_H / (float)GH_);
            const float gwd = __expf(t2) * aw;
            const float ghd = __expf(t3) * ah;
            const float gx1 = gcx - 0.5f * gwd;
            const float gy1 = gcy - 0.5f * ghd;
            const float gx2 = gx1 + gwd;
            const float gy2 = gy1 + ghd;

            const float iw = fmaxf(fminf(px2, gx2) - fmaxf(px1, gx1), 0.0f);
            const float ih = fmaxf(fminf(py2, gy2) - fmaxf(py1, gy1), 0.0f);
            const float inter  = iw * ih;
            const float area_p = (px2 - px1) * (py2 - py1);
            const float area_g = (gx2 - gx1) * (gy2 - gy1);
            const float iou = inter / (area_p + area_g - inter + 1e-9f);
            if (iou < OBJ_THRESH) {
                loss += diff2 * NOOBJ_SCALE;
            }
        }
    }

    // ---- wave-cooperative class CE (density ~0.2% of lanes) ----
    // For each lane with cm!=0, all 64 lanes load the 80 logits in parallel
    // (one ~900cy latency instead of an 80-iter serial strided loop).
    unsigned long long m = __ballot(want_ce);
    while (m) {
        const int src = __ffsll((long long)m) - 1;
        m &= m - 1;
        const unsigned nb  = (unsigned)__shfl((int)nbase, src, 64);
        const int      tcs = __shfl(tc, src, 64);

        const float x0 = net[nb + (unsigned)(5 + lane) * HW_];            // classes 0..63
        const float x1 = (lane < 16) ? net[nb + (unsigned)(69 + lane) * HW_]
                                     : -1e30f;                            // classes 64..79

        float mx = fmaxf(x0, x1);
        #pragma unroll
        for (int off = 32; off > 0; off >>= 1)
            mx = fmaxf(mx, __shfl_xor(mx, off, 64));

        float s = __expf(x0 - mx) + ((lane < 16) ? __expf(x1 - mx) : 0.0f);
        #pragma unroll
        for (int off = 32; off > 0; off >>= 1)
            s += __shfl_xor(s, off, 64);

        const int  idx = (tcs < 64) ? tcs : (tcs - 64);
        const float xa = __shfl(x0, idx, 64);
        const float xb = __shfl(x1, idx, 64);
        const float xt = (tcs < 64) ? xa : xb;

        const float ce = -(xt - mx - __logf(s));
        if (lane == src) loss += ce * CLASS_SCALE;
    }

    // ---- block reduction -> one plain store per block ----
    #pragma unroll
    for (int off = 32; off > 0; off >>= 1)
        loss += __shfl_down(loss, off, 64);

    __shared__ float wsum[4];
    const int wid = threadIdx.x >> 6;
    if (lane == 0) wsum[wid] = loss;
    __syncthreads();
    if (threadIdx.x == 0)
        partial[blockIdx.x] = wsum[0] + wsum[1] + wsum[2] + wsum[3];
}

__global__ __launch_bounds__(256) void yolo_reduce_kernel(
    const float* __restrict__ partial, float* __restrict__ out)
{
    float s = 0.0f;
    for (int j = threadIdx.x; j < GRID; j += BLOCK)
        s += partial[j];

    #pragma unroll
    for (int off = 32; off > 0; off >>= 1)
        s += __shfl_down(s, off, 64);

    __shared__ float w[4];
    const int lane = threadIdx.x & 63;
    const int wid  = threadIdx.x >> 6;
    if (lane == 0) w[wid] = s;
    __syncthreads();
    if (threadIdx.x == 0)
        out[0] = w[0] + w[1] + w[2] + w[3];
}

extern "C" void kernel_launch(void* const* d_in, const int* in_sizes, int n_in,
                              void* d_out, int out_size, void* d_ws, size_t ws_size,
                              hipStream_t stream) {
    const float* net     = (const float*)d_in[0];
    const float* tgt     = (const float*)d_in[1];
    const float* amask   = (const float*)d_in[2];
    const float* omask   = (const float*)d_in[3];
    const float* anchors = (const float*)d_in[4];
    float* out     = (float*)d_out;
    float* partial = (float*)d_ws;   // GRID floats, fully overwritten every launch

    yolo_partial_kernel<<<GRID, BLOCK, 0, stream>>>(net, tgt, amask, omask, anchors, partial);
    yolo_reduce_kernel<<<1, BLOCK, 0, stream>>>(partial, out);
}